// Round 2
// baseline (492.493 us; speedup 1.0000x reference)
//
#include <hip/hip_runtime.h>
#include <hip/hip_bf16.h>
#include <math.h>

#define T_TOK 2048
#define HD 1024
#define ID 2048
#define NE 8

typedef __attribute__((ext_vector_type(8))) short s16x8;
typedef __attribute__((ext_vector_type(4))) float f32x4;
typedef __attribute__((ext_vector_type(4))) unsigned short u16x4;

__device__ __forceinline__ unsigned short f2bf(float f) {
  union { float f; unsigned u; } v; v.f = f;
  unsigned r = v.u + 0x7FFFu + ((v.u >> 16) & 1u);   // round-to-nearest-even
  return (unsigned short)(r >> 16);
}

__device__ __forceinline__ s16x8 pack8(float4 a, float4 b) {
  s16x8 v;
  v[0] = (short)f2bf(a.x); v[1] = (short)f2bf(a.y);
  v[2] = (short)f2bf(a.z); v[3] = (short)f2bf(a.w);
  v[4] = (short)f2bf(b.x); v[5] = (short)f2bf(b.y);
  v[6] = (short)f2bf(b.z); v[7] = (short)f2bf(b.w);
  return v;
}

// ---------------- router: one wave per token ----------------
__global__ void router_k(const float* __restrict__ x, const float* __restrict__ gate,
                         int* __restrict__ cnt, int* __restrict__ tok,
                         float* __restrict__ wt) {
  int wid = threadIdx.x >> 6, lane = threadIdx.x & 63;
  int t = blockIdx.x * 4 + wid;
  const float* xr = x + (size_t)t * HD;
  float acc[NE];
#pragma unroll
  for (int e = 0; e < NE; e++) acc[e] = 0.f;
  for (int h = lane; h < HD; h += 64) {
    float xv = xr[h];
#pragma unroll
    for (int e = 0; e < NE; e++) acc[e] += xv * gate[e * HD + h];
  }
#pragma unroll
  for (int e = 0; e < NE; e++)
    for (int off = 32; off; off >>= 1) acc[e] += __shfl_xor(acc[e], off);
  // top-2 (first-index tie-break, matching jax)
  int i0 = 0;
#pragma unroll
  for (int e = 1; e < NE; e++) if (acc[e] > acc[i0]) i0 = e;
  int i1 = (i0 == 0) ? 1 : 0;
#pragma unroll
  for (int e = 0; e < NE; e++) if (e != i0 && acc[e] > acc[i1]) i1 = e;
  // renormalized top-2 softmax weights: full softmax denom cancels
  float w0 = 1.f / (1.f + expf(acc[i1] - acc[i0]));
  float w1 = 1.f - w0;
  if (lane == 0) {
    int p0 = atomicAdd(&cnt[i0], 1);
    tok[i0 * T_TOK + p0] = t; wt[i0 * T_TOK + p0] = w0;
    int p1 = atomicAdd(&cnt[i1], 1);
    tok[i1 * T_TOK + p1] = t; wt[i1 * T_TOK + p1] = w1;
  }
}

__global__ void prefix_k(const int* __restrict__ cnt, int* __restrict__ offs) {
  if (threadIdx.x == 0) {
    int s = 0;
    for (int e = 0; e < NE; e++) { offs[e] = s; s += cnt[e]; }
  }
}

// gather token rows (fp32 -> bf16), compacted by expert
__global__ void gather_k(const float* __restrict__ x, const int* __restrict__ cnt,
                         const int* __restrict__ offs, const int* __restrict__ tok,
                         unsigned short* __restrict__ Xg) {
  int e = blockIdx.x >> 11, slot = blockIdx.x & 2047;
  if (slot >= cnt[e]) return;
  int t = tok[e * T_TOK + slot];
  int row = offs[e] + slot;
  int c = threadIdx.x * 4;
  float4 f = *(const float4*)(x + (size_t)t * HD + c);
  u16x4 o; o.x = f2bf(f.x); o.y = f2bf(f.y); o.z = f2bf(f.z); o.w = f2bf(f.w);
  *(u16x4*)(Xg + (size_t)row * HD + c) = o;
}

// ---------------- grouped GEMM1: act = silu(Xg@w1^T) * (Xg@w3^T) ----------------
#define BM 128
#define BN 128
#define BK 32
#define LDSS 40   // padded LDS row stride (bf16 elems): 80B -> 2-way conflicts only

__global__ __launch_bounds__(512) void gemm1_k(
    const unsigned short* __restrict__ Xg, const float* __restrict__ w1,
    const float* __restrict__ w3, const int* __restrict__ cnt,
    const int* __restrict__ offs, unsigned short* __restrict__ act) {
  int e = blockIdx.z;
  int count = cnt[e];
  int mt = blockIdx.y;
  if (mt * BM >= count) return;
  int i0 = blockIdx.x * BN;
  int rbase = offs[e] + mt * BM;
  const float* W1 = w1 + (size_t)e * ID * HD;
  const float* W3 = w3 + (size_t)e * ID * HD;

  __shared__ __align__(16) unsigned short As[BM * LDSS];
  __shared__ __align__(16) unsigned short B1s[BM * LDSS];
  __shared__ __align__(16) unsigned short B2s[BM * LDSS];

  int tid = threadIdx.x;
  int srow = tid >> 2;           // 0..127
  int scol = (tid & 3) * 8;      // 0,8,16,24
  int wid = tid >> 6, lane = tid & 63;
  int wr = wid >> 2, wc = wid & 3;          // 2 x 4 wave grid, wave tile 64x32
  int l15 = lane & 15, lk = (lane >> 4) * 8;

  f32x4 accg[4][2], accu[4][2];
#pragma unroll
  for (int m = 0; m < 4; m++)
#pragma unroll
    for (int n = 0; n < 2; n++) {
      accg[m][n] = (f32x4){0.f, 0.f, 0.f, 0.f};
      accu[m][n] = (f32x4){0.f, 0.f, 0.f, 0.f};
    }

  const unsigned short* asrc = Xg + (size_t)(rbase + srow) * HD + scol;
  const float* b1src = W1 + (size_t)(i0 + srow) * HD + scol;
  const float* b2src = W3 + (size_t)(i0 + srow) * HD + scol;

  for (int k0 = 0; k0 < HD; k0 += BK) {
    __syncthreads();
    *(s16x8*)&As[srow * LDSS + scol] = *(const s16x8*)(asrc + k0);
    float4 f0 = *(const float4*)(b1src + k0);
    float4 f1 = *(const float4*)(b1src + k0 + 4);
    *(s16x8*)&B1s[srow * LDSS + scol] = pack8(f0, f1);
    f0 = *(const float4*)(b2src + k0);
    f1 = *(const float4*)(b2src + k0 + 4);
    *(s16x8*)&B2s[srow * LDSS + scol] = pack8(f0, f1);
    __syncthreads();

    s16x8 a[4], b1[2], b2[2];
#pragma unroll
    for (int m = 0; m < 4; m++)
      a[m] = *(const s16x8*)&As[(wr * 64 + m * 16 + l15) * LDSS + lk];
#pragma unroll
    for (int n = 0; n < 2; n++) {
      b1[n] = *(const s16x8*)&B1s[(wc * 32 + n * 16 + l15) * LDSS + lk];
      b2[n] = *(const s16x8*)&B2s[(wc * 32 + n * 16 + l15) * LDSS + lk];
    }
#pragma unroll
    for (int m = 0; m < 4; m++)
#pragma unroll
      for (int n = 0; n < 2; n++) {
        accg[m][n] = __builtin_amdgcn_mfma_f32_16x16x32_bf16(a[m], b1[n], accg[m][n], 0, 0, 0);
        accu[m][n] = __builtin_amdgcn_mfma_f32_16x16x32_bf16(a[m], b2[n], accu[m][n], 0, 0, 0);
      }
  }

  // epilogue: silu(g)*u -> bf16 act (C/D map: col=lane&15, row=(lane>>4)*4+reg)
#pragma unroll
  for (int m = 0; m < 4; m++)
#pragma unroll
    for (int n = 0; n < 2; n++)
#pragma unroll
      for (int r = 0; r < 4; r++) {
        int rl = mt * BM + wr * 64 + m * 16 + (lane >> 4) * 4 + r;
        if (rl < count) {
          float g = accg[m][n][r], u = accu[m][n][r];
          float s = (g / (1.f + expf(-g))) * u;
          act[(size_t)(offs[e] + rl) * ID + i0 + wc * 32 + n * 16 + l15] = f2bf(s);
        }
      }
}

// ---------------- grouped GEMM2: out[t] += w * (act @ w2^T) ----------------
__global__ __launch_bounds__(512) void gemm2_k(
    const unsigned short* __restrict__ act, const float* __restrict__ w2,
    const int* __restrict__ cnt, const int* __restrict__ offs,
    const int* __restrict__ tok, const float* __restrict__ wt,
    float* __restrict__ out) {
  int e = blockIdx.z;
  int count = cnt[e];
  int mt = blockIdx.y;
  if (mt * BM >= count) return;
  int h0 = blockIdx.x * BN;
  int rbase = offs[e] + mt * BM;
  const float* W2 = w2 + (size_t)e * HD * ID;   // [1024][2048]

  __shared__ __align__(16) unsigned short As[BM * LDSS];
  __shared__ __align__(16) unsigned short Bs[BM * LDSS];

  int tid = threadIdx.x;
  int srow = tid >> 2;
  int scol = (tid & 3) * 8;
  int wid = tid >> 6, lane = tid & 63;
  int wr = wid >> 2, wc = wid & 3;
  int l15 = lane & 15, lk = (lane >> 4) * 8;

  f32x4 acc[4][2];
#pragma unroll
  for (int m = 0; m < 4; m++)
#pragma unroll
    for (int n = 0; n < 2; n++) acc[m][n] = (f32x4){0.f, 0.f, 0.f, 0.f};

  const unsigned short* asrc = act + (size_t)(rbase + srow) * ID + scol;
  const float* bsrc = W2 + (size_t)(h0 + srow) * ID + scol;

  for (int k0 = 0; k0 < ID; k0 += BK) {
    __syncthreads();
    *(s16x8*)&As[srow * LDSS + scol] = *(const s16x8*)(asrc + k0);
    float4 f0 = *(const float4*)(bsrc + k0);
    float4 f1 = *(const float4*)(bsrc + k0 + 4);
    *(s16x8*)&Bs[srow * LDSS + scol] = pack8(f0, f1);
    __syncthreads();

    s16x8 a[4], b[2];
#pragma unroll
    for (int m = 0; m < 4; m++)
      a[m] = *(const s16x8*)&As[(wr * 64 + m * 16 + l15) * LDSS + lk];
#pragma unroll
    for (int n = 0; n < 2; n++)
      b[n] = *(const s16x8*)&Bs[(wc * 32 + n * 16 + l15) * LDSS + lk];
#pragma unroll
    for (int m = 0; m < 4; m++)
#pragma unroll
      for (int n = 0; n < 2; n++)
        acc[m][n] = __builtin_amdgcn_mfma_f32_16x16x32_bf16(a[m], b[n], acc[m][n], 0, 0, 0);
  }

#pragma unroll
  for (int m = 0; m < 4; m++)
#pragma unroll
    for (int r = 0; r < 4; r++) {
      int slot = mt * BM + wr * 64 + m * 16 + (lane >> 4) * 4 + r;
      if (slot < count) {
        int t = tok[e * T_TOK + slot];
        float w = wt[e * T_TOK + slot];
#pragma unroll
        for (int n = 0; n < 2; n++) {
          atomicAdd(&out[(size_t)t * HD + h0 + wc * 32 + n * 16 + l15],
                    w * acc[m][n][r]);
        }
      }
    }
}

extern "C" void kernel_launch(void* const* d_in, const int* in_sizes, int n_in,
                              void* d_out, int out_size, void* d_ws, size_t ws_size,
                              hipStream_t stream) {
  const float* x    = (const float*)d_in[0];
  const float* gate = (const float*)d_in[1];
  const float* w1   = (const float*)d_in[2];
  const float* w3   = (const float*)d_in[3];
  const float* w2   = (const float*)d_in[4];
  float* out = (float*)d_out;

  char* ws = (char*)d_ws;
  int* cnt  = (int*)ws;                       // 8 ints
  int* offs = (int*)(ws + 256);               // 8 ints
  int* tok  = (int*)(ws + 512);               // 8*2048 ints
  float* wt = (float*)(ws + 512 + 65536);     // 8*2048 floats
  unsigned short* Xg  = (unsigned short*)(ws + 512 + 2 * 65536);
  unsigned short* act = Xg + (size_t)(4096 + 128) * HD;   // bf16, (4096+128) x ID
  // total ws use: ~26.2 MB

  hipMemsetAsync(cnt, 0, 256, stream);
  hipMemsetAsync(out, 0, (size_t)out_size * sizeof(float), stream);

  router_k<<<T_TOK / 4, 256, 0, stream>>>(x, gate, cnt, tok, wt);
  prefix_k<<<1, 64, 0, stream>>>(cnt, offs);
  gather_k<<<NE * T_TOK, 256, 0, stream>>>(x, cnt, offs, tok, Xg);
  gemm1_k<<<dim3(ID / BN, 16, NE), 512, 0, stream>>>(Xg, w1, w3, cnt, offs, act);
  gemm2_k<<<dim3(HD / BN, 16, NE), 512, 0, stream>>>(act, w2, cnt, offs, tok, wt, out);
}

// Round 3
// 409.808 us; speedup vs baseline: 1.2018x; 1.2018x over previous
//
#include <hip/hip_runtime.h>
#include <hip/hip_bf16.h>
#include <math.h>

#define T_TOK 2048
#define HD 1024
#define ID 2048
#define NE 8

typedef __attribute__((ext_vector_type(8))) short s16x8;
typedef __attribute__((ext_vector_type(8))) unsigned short u16x8;
typedef __attribute__((ext_vector_type(4))) float f32x4;
typedef __attribute__((ext_vector_type(4))) unsigned short u16x4;

__device__ __forceinline__ unsigned short f2bf(float f) {
  union { float f; unsigned u; } v; v.f = f;
  unsigned r = v.u + 0x7FFFu + ((v.u >> 16) & 1u);   // round-to-nearest-even
  return (unsigned short)(r >> 16);
}

// ---------------- weight fp32 -> bf16 conversion ----------------
__global__ void conv_k(const float* __restrict__ src, unsigned short* __restrict__ dst,
                       int nchunk) {
  int stride = gridDim.x * blockDim.x;
  for (int c = blockIdx.x * blockDim.x + threadIdx.x; c < nchunk; c += stride) {
    const float4* s = (const float4*)(src + (size_t)c * 8);
    float4 f0 = s[0], f1 = s[1];
    u16x8 o;
    o[0] = f2bf(f0.x); o[1] = f2bf(f0.y); o[2] = f2bf(f0.z); o[3] = f2bf(f0.w);
    o[4] = f2bf(f1.x); o[5] = f2bf(f1.y); o[6] = f2bf(f1.z); o[7] = f2bf(f1.w);
    *(u16x8*)(dst + (size_t)c * 8) = o;
  }
}

// ---------------- router: one wave per token ----------------
__global__ void router_k(const float* __restrict__ x, const float* __restrict__ gate,
                         int* __restrict__ cnt, int* __restrict__ tok,
                         float* __restrict__ wt, int* __restrict__ inv) {
  int wid = threadIdx.x >> 6, lane = threadIdx.x & 63;
  int t = blockIdx.x * 4 + wid;
  const float* xr = x + (size_t)t * HD;
  float acc[NE];
#pragma unroll
  for (int e = 0; e < NE; e++) acc[e] = 0.f;
  for (int h = lane; h < HD; h += 64) {
    float xv = xr[h];
#pragma unroll
    for (int e = 0; e < NE; e++) acc[e] += xv * gate[e * HD + h];
  }
#pragma unroll
  for (int e = 0; e < NE; e++)
    for (int off = 32; off; off >>= 1) acc[e] += __shfl_xor(acc[e], off);
  int i0 = 0;
#pragma unroll
  for (int e = 1; e < NE; e++) if (acc[e] > acc[i0]) i0 = e;
  int i1 = (i0 == 0) ? 1 : 0;
#pragma unroll
  for (int e = 0; e < NE; e++) if (e != i0 && acc[e] > acc[i1]) i1 = e;
  float w0 = 1.f / (1.f + expf(acc[i1] - acc[i0]));
  float w1 = 1.f - w0;
  if (lane == 0) {
    int p0 = atomicAdd(&cnt[i0], 1);
    tok[i0 * T_TOK + p0] = t; wt[i0 * T_TOK + p0] = w0;
    inv[2 * t] = (i0 << 16) | p0;
    int p1 = atomicAdd(&cnt[i1], 1);
    tok[i1 * T_TOK + p1] = t; wt[i1 * T_TOK + p1] = w1;
    inv[2 * t + 1] = (i1 << 16) | p1;
  }
}

__global__ void prefix_k(const int* __restrict__ cnt, int* __restrict__ offs) {
  if (threadIdx.x == 0) {
    int s = 0;
    for (int e = 0; e < NE; e++) { offs[e] = s; s += cnt[e]; }
  }
}

// gather token rows (fp32 -> bf16), compacted by expert
__global__ void gather_k(const float* __restrict__ x, const int* __restrict__ cnt,
                         const int* __restrict__ offs, const int* __restrict__ tok,
                         unsigned short* __restrict__ Xg) {
  int e = blockIdx.x >> 11, slot = blockIdx.x & 2047;
  if (slot >= cnt[e]) return;
  int t = tok[e * T_TOK + slot];
  int row = offs[e] + slot;
  int c = threadIdx.x * 4;
  float4 f = *(const float4*)(x + (size_t)t * HD + c);
  u16x4 o; o.x = f2bf(f.x); o.y = f2bf(f.y); o.z = f2bf(f.z); o.w = f2bf(f.w);
  *(u16x4*)(Xg + (size_t)row * HD + c) = o;
}

#define LDT 72   // padded LDS row stride for BK=64 tiles: 144B -> 2-way conflicts only (free)

__device__ __forceinline__ void lgkm_barrier() {
  asm volatile("s_waitcnt lgkmcnt(0)" ::: "memory");
  __builtin_amdgcn_s_barrier();
}

// ---------------- grouped GEMM1: act = w * silu(Xg@w1^T) * (Xg@w3^T) ----------------
// 128x128 tile, BK=64, 512 threads (8 waves, 2x4), bf16 weights, reg-prefetch pipeline
__global__ __launch_bounds__(512) void gemm1_k(
    const unsigned short* __restrict__ Xg, const unsigned short* __restrict__ w1b,
    const unsigned short* __restrict__ w3b, const int* __restrict__ cnt,
    const int* __restrict__ offs, const float* __restrict__ wt,
    unsigned short* __restrict__ act) {
  int e = blockIdx.z;
  int count = cnt[e];
  int mt = blockIdx.y;
  if (mt * 128 >= count) return;
  int i0 = blockIdx.x * 128;
  int rbase = offs[e] + mt * 128;
  const unsigned short* W1 = w1b + (size_t)e * ID * HD;
  const unsigned short* W3 = w3b + (size_t)e * ID * HD;

  __shared__ __align__(16) unsigned short As[128 * LDT];
  __shared__ __align__(16) unsigned short B1s[128 * LDT];
  __shared__ __align__(16) unsigned short B2s[128 * LDT];

  int tid = threadIdx.x;
  int ar = tid >> 3, ac = (tid & 7) * 8;      // chunk row 0..63, col-8 within BK
  int wid = tid >> 6, lane = tid & 63;
  int wr = wid >> 2, wc = wid & 3;            // 2x4 wave grid, wave tile 64x32
  int l15 = lane & 15, lk = (lane >> 4) * 8;

  const unsigned short* aS0 = Xg + (size_t)(rbase + ar) * HD + ac;
  const unsigned short* aS1 = aS0 + (size_t)64 * HD;
  const unsigned short* b1S0 = W1 + (size_t)(i0 + ar) * HD + ac;
  const unsigned short* b1S1 = b1S0 + (size_t)64 * HD;
  const unsigned short* b2S0 = W3 + (size_t)(i0 + ar) * HD + ac;
  const unsigned short* b2S1 = b2S0 + (size_t)64 * HD;
  unsigned short* aD0 = &As[ar * LDT + ac];
  unsigned short* aD1 = aD0 + 64 * LDT;
  unsigned short* b1D0 = &B1s[ar * LDT + ac];
  unsigned short* b1D1 = b1D0 + 64 * LDT;
  unsigned short* b2D0 = &B2s[ar * LDT + ac];
  unsigned short* b2D1 = b2D0 + 64 * LDT;

  f32x4 accg[4][2], accu[4][2];
#pragma unroll
  for (int m = 0; m < 4; m++)
#pragma unroll
    for (int n = 0; n < 2; n++) {
      accg[m][n] = (f32x4){0.f, 0.f, 0.f, 0.f};
      accu[m][n] = (f32x4){0.f, 0.f, 0.f, 0.f};
    }

  // prologue: load K-tile 0 into regs
  u16x8 ra0 = *(const u16x8*)aS0, ra1 = *(const u16x8*)aS1;
  u16x8 r10 = *(const u16x8*)b1S0, r11 = *(const u16x8*)b1S1;
  u16x8 r20 = *(const u16x8*)b2S0, r21 = *(const u16x8*)b2S1;

  for (int t = 0; t < 16; ++t) {
    lgkm_barrier();                 // WAR: previous tile's ds_reads complete
    *(u16x8*)aD0 = ra0;  *(u16x8*)aD1 = ra1;
    *(u16x8*)b1D0 = r10; *(u16x8*)b1D1 = r11;
    *(u16x8*)b2D0 = r20; *(u16x8*)b2D1 = r21;
    lgkm_barrier();                 // ds_writes visible to all waves
    if (t < 15) {                   // prefetch next K-tile; lands during compute below
      int k0 = (t + 1) * 64;
      ra0 = *(const u16x8*)(aS0 + k0);  ra1 = *(const u16x8*)(aS1 + k0);
      r10 = *(const u16x8*)(b1S0 + k0); r11 = *(const u16x8*)(b1S1 + k0);
      r20 = *(const u16x8*)(b2S0 + k0); r21 = *(const u16x8*)(b2S1 + k0);
    }
#pragma unroll
    for (int kk = 0; kk < 2; ++kk) {
      s16x8 a[4], b1[2], b2[2];
#pragma unroll
      for (int m = 0; m < 4; m++)
        a[m] = *(const s16x8*)&As[(wr * 64 + m * 16 + l15) * LDT + kk * 32 + lk];
#pragma unroll
      for (int n = 0; n < 2; n++) {
        b1[n] = *(const s16x8*)&B1s[(wc * 32 + n * 16 + l15) * LDT + kk * 32 + lk];
        b2[n] = *(const s16x8*)&B2s[(wc * 32 + n * 16 + l15) * LDT + kk * 32 + lk];
      }
#pragma unroll
      for (int m = 0; m < 4; m++)
#pragma unroll
        for (int n = 0; n < 2; n++) {
          accg[m][n] = __builtin_amdgcn_mfma_f32_16x16x32_bf16(a[m], b1[n], accg[m][n], 0, 0, 0);
          accu[m][n] = __builtin_amdgcn_mfma_f32_16x16x32_bf16(a[m], b2[n], accu[m][n], 0, 0, 0);
        }
    }
  }

  // epilogue: w * silu(g) * u -> bf16 act (C/D map: col=lane&15, row=(lane>>4)*4+reg)
#pragma unroll
  for (int m = 0; m < 4; m++)
#pragma unroll
    for (int r = 0; r < 4; r++) {
      int rl = mt * 128 + wr * 64 + m * 16 + (lane >> 4) * 4 + r;
      if (rl < count) {
        float w = wt[e * T_TOK + rl];
#pragma unroll
        for (int n = 0; n < 2; n++) {
          float g = accg[m][n][r], u = accu[m][n][r];
          float s = (g / (1.f + expf(-g))) * u * w;
          act[(size_t)(offs[e] + rl) * ID + i0 + wc * 32 + n * 16 + l15] = f2bf(s);
        }
      }
    }
}

// ---------------- grouped GEMM2: ye = act @ w2^T (plain stores) ----------------
// 64x128 tile, BK=64, 256 threads (4 waves, 1x4)
__global__ __launch_bounds__(256) void gemm2_k(
    const unsigned short* __restrict__ act, const unsigned short* __restrict__ w2b,
    const int* __restrict__ cnt, const int* __restrict__ offs,
    float* __restrict__ ye) {
  int e = blockIdx.z;
  int count = cnt[e];
  int mt = blockIdx.y;
  if (mt * 64 >= count) return;
  int h0 = blockIdx.x * 128;
  int rbase = offs[e] + mt * 64;
  const unsigned short* W2 = w2b + (size_t)e * HD * ID;   // [1024][2048] bf16

  __shared__ __align__(16) unsigned short As[64 * LDT];
  __shared__ __align__(16) unsigned short Bs[128 * LDT];

  int tid = threadIdx.x;
  int ar = tid >> 3, ac = (tid & 7) * 8;      // chunk row 0..31
  int wc = tid >> 6, lane = tid & 63;         // wave grid 1x4
  int l15 = lane & 15, lk = (lane >> 4) * 8;

  const unsigned short* aS0 = act + (size_t)(rbase + ar) * ID + ac;
  const unsigned short* aS1 = aS0 + (size_t)32 * ID;
  const unsigned short* bS0 = W2 + (size_t)(h0 + ar) * ID + ac;
  const unsigned short* bS1 = bS0 + (size_t)32 * ID;
  const unsigned short* bS2 = bS0 + (size_t)64 * ID;
  const unsigned short* bS3 = bS0 + (size_t)96 * ID;
  unsigned short* aD0 = &As[ar * LDT + ac];
  unsigned short* aD1 = aD0 + 32 * LDT;
  unsigned short* bD0 = &Bs[ar * LDT + ac];
  unsigned short* bD1 = bD0 + 32 * LDT;
  unsigned short* bD2 = bD0 + 64 * LDT;
  unsigned short* bD3 = bD0 + 96 * LDT;

  f32x4 acc[4][2];
#pragma unroll
  for (int m = 0; m < 4; m++)
#pragma unroll
    for (int n = 0; n < 2; n++) acc[m][n] = (f32x4){0.f, 0.f, 0.f, 0.f};

  u16x8 ra0 = *(const u16x8*)aS0, ra1 = *(const u16x8*)aS1;
  u16x8 rb0 = *(const u16x8*)bS0, rb1 = *(const u16x8*)bS1;
  u16x8 rb2 = *(const u16x8*)bS2, rb3 = *(const u16x8*)bS3;

  for (int t = 0; t < 32; ++t) {
    lgkm_barrier();
    *(u16x8*)aD0 = ra0; *(u16x8*)aD1 = ra1;
    *(u16x8*)bD0 = rb0; *(u16x8*)bD1 = rb1;
    *(u16x8*)bD2 = rb2; *(u16x8*)bD3 = rb3;
    lgkm_barrier();
    if (t < 31) {
      int k0 = (t + 1) * 64;
      ra0 = *(const u16x8*)(aS0 + k0); ra1 = *(const u16x8*)(aS1 + k0);
      rb0 = *(const u16x8*)(bS0 + k0); rb1 = *(const u16x8*)(bS1 + k0);
      rb2 = *(const u16x8*)(bS2 + k0); rb3 = *(const u16x8*)(bS3 + k0);
    }
#pragma unroll
    for (int kk = 0; kk < 2; ++kk) {
      s16x8 a[4], b[2];
#pragma unroll
      for (int m = 0; m < 4; m++)
        a[m] = *(const s16x8*)&As[(m * 16 + l15) * LDT + kk * 32 + lk];
#pragma unroll
      for (int n = 0; n < 2; n++)
        b[n] = *(const s16x8*)&Bs[(wc * 32 + n * 16 + l15) * LDT + kk * 32 + lk];
#pragma unroll
      for (int m = 0; m < 4; m++)
#pragma unroll
        for (int n = 0; n < 2; n++)
          acc[m][n] = __builtin_amdgcn_mfma_f32_16x16x32_bf16(a[m], b[n], acc[m][n], 0, 0, 0);
    }
  }

#pragma unroll
  for (int m = 0; m < 4; m++)
#pragma unroll
    for (int r = 0; r < 4; r++) {
      int slot = mt * 64 + m * 16 + (lane >> 4) * 4 + r;
      if (slot < count) {
#pragma unroll
        for (int n = 0; n < 2; n++)
          ye[(size_t)(offs[e] + slot) * HD + h0 + wc * 32 + n * 16 + l15] = acc[m][n][r];
      }
    }
}

// ---------------- combine: out[t] = ye[slot0] + ye[slot1] ----------------
__global__ void combine_k(const float* __restrict__ ye, const int* __restrict__ inv,
                          const int* __restrict__ offs, float* __restrict__ out) {
  int t = blockIdx.x;
  int c = threadIdx.x * 4;
  int v0 = inv[2 * t], v1 = inv[2 * t + 1];
  int r0 = offs[v0 >> 16] + (v0 & 0xFFFF);
  int r1 = offs[v1 >> 16] + (v1 & 0xFFFF);
  float4 a = *(const float4*)(ye + (size_t)r0 * HD + c);
  float4 b = *(const float4*)(ye + (size_t)r1 * HD + c);
  float4 o = {a.x + b.x, a.y + b.y, a.z + b.z, a.w + b.w};
  *(float4*)(out + (size_t)t * HD + c) = o;
}

extern "C" void kernel_launch(void* const* d_in, const int* in_sizes, int n_in,
                              void* d_out, int out_size, void* d_ws, size_t ws_size,
                              hipStream_t stream) {
  const float* x    = (const float*)d_in[0];
  const float* gate = (const float*)d_in[1];
  const float* w1   = (const float*)d_in[2];
  const float* w3   = (const float*)d_in[3];
  const float* w2   = (const float*)d_in[4];
  float* out = (float*)d_out;

  char* ws = (char*)d_ws;
  int* cnt  = (int*)(ws + 0);
  int* offs = (int*)(ws + 256);
  int* tok  = (int*)(ws + 512);                          // 8*2048*4 = 64K
  float* wt = (float*)(ws + 66048);                      // 64K
  int* inv  = (int*)(ws + 131584);                       // 16K
  unsigned short* Xg  = (unsigned short*)(ws + 148480);  // 4224*1024*2 = 8.65M
  unsigned short* act = (unsigned short*)(ws + 8799232); // 4224*2048*2 = 17.3M
  float* ye = (float*)(ws + 26100736);                   // 4224*1024*4 = 17.3M
  unsigned short* w1b = (unsigned short*)(ws + 43402240);  // 33.55M
  unsigned short* w3b = (unsigned short*)(ws + 76956672);  // 33.55M
  unsigned short* w2b = (unsigned short*)(ws + 110511104); // 33.55M -> ends 144.07M

  hipMemsetAsync(cnt, 0, 256, stream);

  const int WCHUNK = (NE * ID * HD) / 8;   // 2,097,152 chunks per weight tensor
  conv_k<<<2048, 256, 0, stream>>>(w1, w1b, WCHUNK);
  conv_k<<<2048, 256, 0, stream>>>(w3, w3b, WCHUNK);
  conv_k<<<2048, 256, 0, stream>>>(w2, w2b, WCHUNK);

  router_k<<<T_TOK / 4, 256, 0, stream>>>(x, gate, cnt, tok, wt, inv);
  prefix_k<<<1, 64, 0, stream>>>(cnt, offs);
  gather_k<<<NE * T_TOK, 256, 0, stream>>>(x, cnt, offs, tok, Xg);
  gemm1_k<<<dim3(ID / 128, 16, NE), 512, 0, stream>>>(Xg, w1b, w3b, cnt, offs, wt, act);
  gemm2_k<<<dim3(HD / 128, 32, NE), 256, 0, stream>>>(act, w2b, cnt, offs, ye);
  combine_k<<<T_TOK, 256, 0, stream>>>(ye, inv, offs, out);
}

// Round 4
// 371.065 us; speedup vs baseline: 1.3272x; 1.1044x over previous
//
#include <hip/hip_runtime.h>
#include <hip/hip_bf16.h>
#include <math.h>

#define T_TOK 2048
#define HD 1024
#define ID 2048
#define NE 8
#define LDT 72   // padded bf16 row stride for [64][64] weight tiles (144B -> 2-way, free)

typedef __attribute__((ext_vector_type(8))) short s16x8;
typedef __attribute__((ext_vector_type(8))) unsigned short u16x8;
typedef __attribute__((ext_vector_type(4))) float f32x4;
typedef __attribute__((ext_vector_type(4))) unsigned short u16x4;

__device__ __forceinline__ unsigned short f2bf(float f) {
  union { float f; unsigned u; } v; v.f = f;
  unsigned r = v.u + 0x7FFFu + ((v.u >> 16) & 1u);   // round-to-nearest-even
  return (unsigned short)(r >> 16);
}

__device__ __forceinline__ u16x8 pack8(float4 a, float4 b) {
  u16x8 v;
  v[0] = f2bf(a.x); v[1] = f2bf(a.y); v[2] = f2bf(a.z); v[3] = f2bf(a.w);
  v[4] = f2bf(b.x); v[5] = f2bf(b.y); v[6] = f2bf(b.z); v[7] = f2bf(b.w);
  return v;
}

__device__ __forceinline__ void lgkm_barrier() {
  asm volatile("s_waitcnt lgkmcnt(0)" ::: "memory");
  __builtin_amdgcn_s_barrier();
}

#define GLOAD16(gsrc, ldst) \
  __builtin_amdgcn_global_load_lds((const __attribute__((address_space(1))) void*)(gsrc), \
                                   (__attribute__((address_space(3))) void*)(ldst), 16, 0, 0)

// ---------------- router: one wave per token ----------------
__global__ void router_k(const float* __restrict__ x, const float* __restrict__ gate,
                         int* __restrict__ cnt, int* __restrict__ tok,
                         float* __restrict__ wt, int* __restrict__ inv) {
  int wid = threadIdx.x >> 6, lane = threadIdx.x & 63;
  int t = blockIdx.x * 4 + wid;
  const float* xr = x + (size_t)t * HD;
  float acc[NE];
#pragma unroll
  for (int e = 0; e < NE; e++) acc[e] = 0.f;
  for (int h = lane; h < HD; h += 64) {
    float xv = xr[h];
#pragma unroll
    for (int e = 0; e < NE; e++) acc[e] += xv * gate[e * HD + h];
  }
#pragma unroll
  for (int e = 0; e < NE; e++)
    for (int off = 32; off; off >>= 1) acc[e] += __shfl_xor(acc[e], off);
  int i0 = 0;
#pragma unroll
  for (int e = 1; e < NE; e++) if (acc[e] > acc[i0]) i0 = e;
  int i1 = (i0 == 0) ? 1 : 0;
#pragma unroll
  for (int e = 0; e < NE; e++) if (e != i0 && acc[e] > acc[i1]) i1 = e;
  float w0 = 1.f / (1.f + expf(acc[i1] - acc[i0]));
  float w1 = 1.f - w0;
  if (lane == 0) {
    int p0 = atomicAdd(&cnt[i0], 1);
    tok[i0 * T_TOK + p0] = t; wt[i0 * T_TOK + p0] = w0;
    inv[2 * t] = (i0 << 16) | p0;
    int p1 = atomicAdd(&cnt[i1], 1);
    tok[i1 * T_TOK + p1] = t; wt[i1 * T_TOK + p1] = w1;
    inv[2 * t + 1] = (i1 << 16) | p1;
  }
}

__global__ void prefix_k(const int* __restrict__ cnt, int* __restrict__ offs) {
  if (threadIdx.x == 0) {
    int s = 0;
    for (int e = 0; e < NE; e++) { offs[e] = s; s += cnt[e]; }
  }
}

// gather token rows (fp32 -> bf16), compacted by expert
__global__ void gather_k(const float* __restrict__ x, const int* __restrict__ cnt,
                         const int* __restrict__ offs, const int* __restrict__ tok,
                         unsigned short* __restrict__ Xg) {
  int e = blockIdx.x >> 11, slot = blockIdx.x & 2047;
  if (slot >= cnt[e]) return;
  int t = tok[e * T_TOK + slot];
  int row = offs[e] + slot;
  int c = threadIdx.x * 4;
  float4 f = *(const float4*)(x + (size_t)t * HD + c);
  u16x4 o; o.x = f2bf(f.x); o.y = f2bf(f.y); o.z = f2bf(f.z); o.w = f2bf(f.w);
  *(u16x4*)(Xg + (size_t)row * HD + c) = o;
}

// ---------------- grouped GEMM1: act = w * silu(Xg@w1^T) * (Xg@w3^T) ----------------
// 256 thr (4 waves 2x2), tile 128(M)x64(N), BK=64.
// A: global_load_lds (bf16, dbuf, XOR-swizzled via pre-swizzled source).
// B1/B2: fp32 -> reg -> bf16 -> LDS, 1-deep prefetch.
__global__ __launch_bounds__(256, 3) void gemm1_k(
    const unsigned short* __restrict__ Xg, const float* __restrict__ w1,
    const float* __restrict__ w3, const int* __restrict__ cnt,
    const int* __restrict__ offs, const float* __restrict__ wt,
    unsigned short* __restrict__ act) {
  int e = blockIdx.z;
  int count = cnt[e];
  int mt = blockIdx.y;
  if (mt * 128 >= count) return;
  int i0 = blockIdx.x * 64;
  int rbase = offs[e] + mt * 128;
  const float* W1 = w1 + (size_t)e * ID * HD;
  const float* W3 = w3 + (size_t)e * ID * HD;

  __shared__ __align__(16) unsigned short Abuf[2][128 * 64];  // linear+swz, 16KB each
  __shared__ __align__(16) unsigned short B1s[64 * LDT];
  __shared__ __align__(16) unsigned short B2s[64 * LDT];

  int tid = threadIdx.x;
  int wid = tid >> 6, lane = tid & 63;
  int wr = wid >> 1, wc = wid & 1;          // 2x2 waves, wave tile 64x32
  int l15 = lane & 15, hi = lane >> 4;
  int br = tid >> 2, bc = (tid & 3) * 16;   // weight staging: row 0..63, 16 elems

  // A stage: chunk c covers rows c*32+wid*8+(lane>>3); source col pre-swizzled
  int swz_col = ((lane & 7) ^ (lane >> 3)) * 8;
  const unsigned short* ag[4];
#pragma unroll
  for (int c = 0; c < 4; c++)
    ag[c] = Xg + (size_t)(rbase + c * 32 + wid * 8 + (lane >> 3)) * HD + swz_col;

  const float* s1 = W1 + (size_t)(i0 + br) * HD + bc;
  const float* s2 = W3 + (size_t)(i0 + br) * HD + bc;

  f32x4 accg[4][2], accu[4][2];
#pragma unroll
  for (int m = 0; m < 4; m++)
#pragma unroll
    for (int n = 0; n < 2; n++) {
      accg[m][n] = (f32x4){0.f, 0.f, 0.f, 0.f};
      accu[m][n] = (f32x4){0.f, 0.f, 0.f, 0.f};
    }

  // prologue: tile 0 (A gloads first, then weight loads — order matters for vmcnt)
#pragma unroll
  for (int c = 0; c < 4; c++) GLOAD16(ag[c], &Abuf[0][c * 2048 + wid * 512]);
  float4 p1[4], p2[4];
#pragma unroll
  for (int j = 0; j < 4; j++) { p1[j] = *(const float4*)(s1 + j * 4); p2[j] = *(const float4*)(s2 + j * 4); }

  for (int t = 0; t < 16; ++t) {
    int cur = t & 1;
    lgkm_barrier();   // all waves' previous ds_reads complete (WAR for B write & A dbuf)
    // ds_write waits vmcnt for p-regs (last issued) -> also drains this tile's A gloads
    *(u16x8*)&B1s[br * LDT + bc]     = pack8(p1[0], p1[1]);
    *(u16x8*)&B1s[br * LDT + bc + 8] = pack8(p1[2], p1[3]);
    *(u16x8*)&B2s[br * LDT + bc]     = pack8(p2[0], p2[1]);
    *(u16x8*)&B2s[br * LDT + bc + 8] = pack8(p2[2], p2[3]);
    lgkm_barrier();   // B visible + A[cur] complete for all waves
    __builtin_amdgcn_sched_barrier(0);
    if (t < 15) {     // prefetch tile t+1: A -> LDS dbuf, weights -> regs
      int k0n = (t + 1) * 64;
#pragma unroll
      for (int c = 0; c < 4; c++)
        GLOAD16(ag[c] + k0n, &Abuf[cur ^ 1][c * 2048 + wid * 512]);
#pragma unroll
      for (int j = 0; j < 4; j++) {
        p1[j] = *(const float4*)(s1 + k0n + j * 4);
        p2[j] = *(const float4*)(s2 + k0n + j * 4);
      }
    }
#pragma unroll
    for (int kk = 0; kk < 2; ++kk) {
      s16x8 a[4], b1[2], b2[2];
#pragma unroll
      for (int m = 0; m < 4; m++) {
        int r = wr * 64 + m * 16 + l15;
        a[m] = *(const s16x8*)&Abuf[cur][r * 64 + (((kk * 4 + hi) ^ (r & 7)) * 8)];
      }
#pragma unroll
      for (int n = 0; n < 2; n++) {
        b1[n] = *(const s16x8*)&B1s[(wc * 32 + n * 16 + l15) * LDT + kk * 32 + hi * 8];
        b2[n] = *(const s16x8*)&B2s[(wc * 32 + n * 16 + l15) * LDT + kk * 32 + hi * 8];
      }
#pragma unroll
      for (int m = 0; m < 4; m++)
#pragma unroll
        for (int n = 0; n < 2; n++) {
          accg[m][n] = __builtin_amdgcn_mfma_f32_16x16x32_bf16(a[m], b1[n], accg[m][n], 0, 0, 0);
          accu[m][n] = __builtin_amdgcn_mfma_f32_16x16x32_bf16(a[m], b2[n], accu[m][n], 0, 0, 0);
        }
    }
  }

  // epilogue: w * silu(g) * u -> bf16 act (C/D map: col=lane&15, row=(lane>>4)*4+reg)
#pragma unroll
  for (int m = 0; m < 4; m++)
#pragma unroll
    for (int r = 0; r < 4; r++) {
      int rl = mt * 128 + wr * 64 + m * 16 + (lane >> 4) * 4 + r;
      if (rl < count) {
        float w = wt[e * T_TOK + rl];
#pragma unroll
        for (int n = 0; n < 2; n++) {
          float g = accg[m][n][r], u = accu[m][n][r];
          float s = (g / (1.f + expf(-g))) * u * w;
          act[(size_t)(offs[e] + rl) * ID + i0 + wc * 32 + n * 16 + l15] = f2bf(s);
        }
      }
    }
}

// ---------------- grouped GEMM2: ye = act @ w2^T ----------------
// 256 thr (4 waves 2x2), tile 128(M)x64(N of HD), BK=64, K=ID=2048.
__global__ __launch_bounds__(256, 3) void gemm2_k(
    const unsigned short* __restrict__ act, const float* __restrict__ w2,
    const int* __restrict__ cnt, const int* __restrict__ offs,
    float* __restrict__ ye) {
  int e = blockIdx.z;
  int count = cnt[e];
  int mt = blockIdx.y;
  if (mt * 128 >= count) return;
  int h0 = blockIdx.x * 64;
  int rbase = offs[e] + mt * 128;
  const float* W2 = w2 + (size_t)e * HD * ID;   // [1024][2048]

  __shared__ __align__(16) unsigned short Abuf[2][128 * 64];
  __shared__ __align__(16) unsigned short Bs[64 * LDT];

  int tid = threadIdx.x;
  int wid = tid >> 6, lane = tid & 63;
  int wr = wid >> 1, wc = wid & 1;
  int l15 = lane & 15, hi = lane >> 4;
  int br = tid >> 2, bc = (tid & 3) * 16;

  int swz_col = ((lane & 7) ^ (lane >> 3)) * 8;
  const unsigned short* ag[4];
#pragma unroll
  for (int c = 0; c < 4; c++)
    ag[c] = act + (size_t)(rbase + c * 32 + wid * 8 + (lane >> 3)) * ID + swz_col;

  const float* sb = W2 + (size_t)(h0 + br) * ID + bc;

  f32x4 acc[4][2];
#pragma unroll
  for (int m = 0; m < 4; m++)
#pragma unroll
    for (int n = 0; n < 2; n++) acc[m][n] = (f32x4){0.f, 0.f, 0.f, 0.f};

#pragma unroll
  for (int c = 0; c < 4; c++) GLOAD16(ag[c], &Abuf[0][c * 2048 + wid * 512]);
  float4 pb[4];
#pragma unroll
  for (int j = 0; j < 4; j++) pb[j] = *(const float4*)(sb + j * 4);

  for (int t = 0; t < 32; ++t) {
    int cur = t & 1;
    lgkm_barrier();
    *(u16x8*)&Bs[br * LDT + bc]     = pack8(pb[0], pb[1]);
    *(u16x8*)&Bs[br * LDT + bc + 8] = pack8(pb[2], pb[3]);
    lgkm_barrier();
    __builtin_amdgcn_sched_barrier(0);
    if (t < 31) {
      int k0n = (t + 1) * 64;
#pragma unroll
      for (int c = 0; c < 4; c++)
        GLOAD16(ag[c] + k0n, &Abuf[cur ^ 1][c * 2048 + wid * 512]);
#pragma unroll
      for (int j = 0; j < 4; j++) pb[j] = *(const float4*)(sb + k0n + j * 4);
    }
#pragma unroll
    for (int kk = 0; kk < 2; ++kk) {
      s16x8 a[4], b[2];
#pragma unroll
      for (int m = 0; m < 4; m++) {
        int r = wr * 64 + m * 16 + l15;
        a[m] = *(const s16x8*)&Abuf[cur][r * 64 + (((kk * 4 + hi) ^ (r & 7)) * 8)];
      }
#pragma unroll
      for (int n = 0; n < 2; n++)
        b[n] = *(const s16x8*)&Bs[(wc * 32 + n * 16 + l15) * LDT + kk * 32 + hi * 8];
#pragma unroll
      for (int m = 0; m < 4; m++)
#pragma unroll
        for (int n = 0; n < 2; n++)
          acc[m][n] = __builtin_amdgcn_mfma_f32_16x16x32_bf16(a[m], b[n], acc[m][n], 0, 0, 0);
    }
  }

#pragma unroll
  for (int m = 0; m < 4; m++)
#pragma unroll
    for (int r = 0; r < 4; r++) {
      int slot = mt * 128 + wr * 64 + m * 16 + (lane >> 4) * 4 + r;
      if (slot < count) {
#pragma unroll
        for (int n = 0; n < 2; n++)
          ye[(size_t)(offs[e] + slot) * HD + h0 + wc * 32 + n * 16 + l15] = acc[m][n][r];
      }
    }
}

// ---------------- combine: out[t] = ye[slot0] + ye[slot1] ----------------
__global__ void combine_k(const float* __restrict__ ye, const int* __restrict__ inv,
                          const int* __restrict__ offs, float* __restrict__ out) {
  int t = blockIdx.x;
  int c = threadIdx.x * 4;
  int v0 = inv[2 * t], v1 = inv[2 * t + 1];
  int r0 = offs[v0 >> 16] + (v0 & 0xFFFF);
  int r1 = offs[v1 >> 16] + (v1 & 0xFFFF);
  float4 a = *(const float4*)(ye + (size_t)r0 * HD + c);
  float4 b = *(const float4*)(ye + (size_t)r1 * HD + c);
  float4 o = {a.x + b.x, a.y + b.y, a.z + b.z, a.w + b.w};
  *(float4*)(out + (size_t)t * HD + c) = o;
}

extern "C" void kernel_launch(void* const* d_in, const int* in_sizes, int n_in,
                              void* d_out, int out_size, void* d_ws, size_t ws_size,
                              hipStream_t stream) {
  const float* x    = (const float*)d_in[0];
  const float* gate = (const float*)d_in[1];
  const float* w1   = (const float*)d_in[2];
  const float* w3   = (const float*)d_in[3];
  const float* w2   = (const float*)d_in[4];
  float* out = (float*)d_out;

  char* ws = (char*)d_ws;
  int* cnt  = (int*)(ws + 0);
  int* offs = (int*)(ws + 256);
  int* tok  = (int*)(ws + 512);                          // 8*2048*4 = 64K
  float* wt = (float*)(ws + 66048);                      // 64K
  int* inv  = (int*)(ws + 131584);                       // 16K
  unsigned short* Xg  = (unsigned short*)(ws + 148480);  // 4224*1024*2 = 8.65M
  unsigned short* act = (unsigned short*)(ws + 8799232); // 4224*2048*2 = 17.3M
  float* ye = (float*)(ws + 26100736);                   // 4224*1024*4 = 17.3M -> ends ~43.4M

  hipMemsetAsync(cnt, 0, 256, stream);

  router_k<<<T_TOK / 4, 256, 0, stream>>>(x, gate, cnt, tok, wt, inv);
  prefix_k<<<1, 64, 0, stream>>>(cnt, offs);
  gather_k<<<NE * T_TOK, 256, 0, stream>>>(x, cnt, offs, tok, Xg);
  gemm1_k<<<dim3(ID / 64, 16, NE), 256, 0, stream>>>(Xg, w1, w3, cnt, offs, wt, act);
  gemm2_k<<<dim3(HD / 64, 16, NE), 256, 0, stream>>>(act, w2, cnt, offs, ye);
  combine_k<<<T_TOK, 256, 0, stream>>>(ye, inv, offs, out);
}